// Round 1
// baseline (1777.903 us; speedup 1.0000x reference)
//
#include <hip/hip_runtime.h>
#include <math.h>

#define BD 8
#define ND 1024
#define KNN 20
#define NEGS 0.2f
#define BNSC 0.99999500003749969482f

__device__ __forceinline__ float leakyf(float y){ return y >= 0.f ? y : NEGS*y; }

// ---------------- layer-0 input slice: x[b,n,c] = feat[b, c0+c, n] ----------------
__global__ __launch_bounds__(256) void k_transpose_in(const float* __restrict__ feat,
                                                      float* __restrict__ x, int c0, int C){
  int i = blockIdx.x*256 + threadIdx.x;
  int total = BD*ND*C;
  if (i >= total) return;
  int c = i % C; int n = (i / C) % ND; int b = i / (C*ND);
  x[i] = feat[((size_t)b*15 + c0 + c)*ND + n];
}

// ---------------- xx[b,n] = sum_c x^2 (same fmaf chain order as gram) ----------------
__global__ __launch_bounds__(256) void k_xx(const float* __restrict__ x,
                                            float* __restrict__ xx, int C){
  int i = blockIdx.x*256 + threadIdx.x;
  if (i >= BD*ND) return;
  const float* p = x + (size_t)i*C;
  float s = 0.f;
  for (int c = 0; c < C; ++c) s = fmaf(p[c], p[c], s);
  xx[i] = s;
}

// ---------------- negdist[b,n,m] = 2*dot - xx[n] - xx[m]; 64x64 tiles, 4x4/thread ----
__global__ __launch_bounds__(256) void k_gram(const float* __restrict__ x,
                                              const float* __restrict__ xx,
                                              float* __restrict__ nd, int C){
  __shared__ __align__(16) float At[32][68];
  __shared__ __align__(16) float Bt[32][68];
  int b = blockIdx.z;
  int r0 = blockIdx.y*64, c0 = blockIdx.x*64;
  int t = threadIdx.x;
  int tr = t >> 4, tc = t & 15;
  float acc[4][4] = {};
  const float* xb = x + (size_t)b*ND*C;
  for (int cc = 0; cc < C; cc += 32){
    for (int i = t; i < 64*32; i += 256){
      int row = i >> 5, c = i & 31;
      float av = 0.f, bv = 0.f;
      if (cc + c < C){
        av = xb[(size_t)(r0+row)*C + cc + c];
        bv = xb[(size_t)(c0+row)*C + cc + c];
      }
      At[c][row] = av;
      Bt[c][row] = bv;
    }
    __syncthreads();
    #pragma unroll 4
    for (int c = 0; c < 32; ++c){
      float4 a4 = *(const float4*)&At[c][tr*4];
      float4 b4 = *(const float4*)&Bt[c][tc*4];
      acc[0][0]=fmaf(a4.x,b4.x,acc[0][0]); acc[0][1]=fmaf(a4.x,b4.y,acc[0][1]);
      acc[0][2]=fmaf(a4.x,b4.z,acc[0][2]); acc[0][3]=fmaf(a4.x,b4.w,acc[0][3]);
      acc[1][0]=fmaf(a4.y,b4.x,acc[1][0]); acc[1][1]=fmaf(a4.y,b4.y,acc[1][1]);
      acc[1][2]=fmaf(a4.y,b4.z,acc[1][2]); acc[1][3]=fmaf(a4.y,b4.w,acc[1][3]);
      acc[2][0]=fmaf(a4.z,b4.x,acc[2][0]); acc[2][1]=fmaf(a4.z,b4.y,acc[2][1]);
      acc[2][2]=fmaf(a4.z,b4.z,acc[2][2]); acc[2][3]=fmaf(a4.z,b4.w,acc[2][3]);
      acc[3][0]=fmaf(a4.w,b4.x,acc[3][0]); acc[3][1]=fmaf(a4.w,b4.y,acc[3][1]);
      acc[3][2]=fmaf(a4.w,b4.z,acc[3][2]); acc[3][3]=fmaf(a4.w,b4.w,acc[3][3]);
    }
    __syncthreads();
  }
  float xr[4], xm[4];
  #pragma unroll
  for (int i = 0; i < 4; ++i) xr[i] = xx[b*ND + r0 + tr*4 + i];
  #pragma unroll
  for (int j = 0; j < 4; ++j) xm[j] = xx[b*ND + c0 + tc*4 + j];
  #pragma unroll
  for (int i = 0; i < 4; ++i){
    float4 st;
    st.x = 2.f*acc[i][0] - xr[i] - xm[0];
    st.y = 2.f*acc[i][1] - xr[i] - xm[1];
    st.z = 2.f*acc[i][2] - xr[i] - xm[2];
    st.w = 2.f*acc[i][3] - xr[i] - xm[3];
    *(float4*)&nd[((size_t)b*ND + r0 + tr*4 + i)*ND + c0 + tc*4] = st;
  }
}

// ---------------- top-20 per row; one wave per row, regs only ----------------
__global__ __launch_bounds__(256) void k_topk(const float* __restrict__ nd,
                                              int* __restrict__ idxp){
  int t = threadIdx.x;
  int lane = t & 63, w = t >> 6;
  int rid = blockIdx.x*4 + w;
  const float* src = nd + (size_t)rid*ND;
  float vals[16];
  #pragma unroll
  for (int q = 0; q < 16; ++q) vals[q] = src[q*64 + lane];
  int* op = idxp + (size_t)rid*KNN;
  for (int kk = 0; kk < KNN; ++kk){
    float bv = -INFINITY; int bi = 0x7fffffff;
    #pragma unroll
    for (int q = 0; q < 16; ++q){
      if (vals[q] > bv){ bv = vals[q]; bi = q*64 + lane; }
    }
    #pragma unroll
    for (int off = 32; off; off >>= 1){
      float ov = __shfl_down(bv, off);
      int   oi = __shfl_down(bi, off);
      if (ov > bv || (ov == bv && oi < bi)){ bv = ov; bi = oi; }
    }
    bi = __shfl(bi, 0);
    if (lane == 0) op[kk] = bi;
    #pragma unroll
    for (int q = 0; q < 16; ++q) if (q*64 + lane == bi) vals[q] = -INFINITY;
  }
}

// ---------------- phase A: zs[b,n,o]=alpha*W1.x_n ; cc=(dW.x_n+bias)*alpha+beta ------
template<int O>
__global__ __launch_bounds__(256) void k_phaseA(const float* __restrict__ x,
    const float* __restrict__ W, const float* __restrict__ bias,
    const float* __restrict__ gamma, const float* __restrict__ beta,
    float* __restrict__ zs, float* __restrict__ ccv, int C){
  constexpr int NP = 256 / O;
  constexpr int P  = 32 / NP;
  __shared__ float W1s[128*33];
  __shared__ float dWs[128*33];
  __shared__ float Xs[32*33];
  int blk = blockIdx.x;
  int b = blk / (ND/32), n0 = (blk % (ND/32))*32;
  int t = threadIdx.x;
  int o = t % O;
  int j = t / O;
  float az[P], ac[P];
  #pragma unroll
  for (int p = 0; p < P; ++p){ az[p] = 0.f; ac[p] = 0.f; }
  for (int cc = 0; cc < C; cc += 32){
    int KC = (C - cc < 32) ? (C - cc) : 32;
    for (int i = t; i < O*KC; i += 256){
      int oo = i / KC, c = i % KC;
      float w1 = W[(size_t)oo*2*C + cc + c];
      float w2 = W[(size_t)oo*2*C + C + cc + c];
      W1s[oo*33 + c] = w1;
      dWs[oo*33 + c] = w2 - w1;
    }
    for (int i = t; i < 32*KC; i += 256){
      int row = i / KC, c = i % KC;
      Xs[row*33 + c] = x[((size_t)b*ND + n0 + row)*C + cc + c];
    }
    __syncthreads();
    for (int c = 0; c < KC; ++c){
      float wv = W1s[o*33 + c];
      float dv = dWs[o*33 + c];
      #pragma unroll
      for (int p = 0; p < P; ++p){
        float xv = Xs[(p*NP + j)*33 + c];
        az[p] = fmaf(wv, xv, az[p]);
        ac[p] = fmaf(dv, xv, ac[p]);
      }
    }
    __syncthreads();
  }
  float alpha = gamma[o]*BNSC;
  float bb = bias[o], be = beta[o];
  #pragma unroll
  for (int p = 0; p < P; ++p){
    int n = n0 + p*NP + j;
    size_t off = ((size_t)b*ND + n)*O + o;
    zs[off] = az[p]*alpha;
    ccv[off] = fmaf(ac[p] + bb, alpha, be);
  }
}

// ---------------- phase B: out[b,n,o] = max_k leaky(zs[b,idx_k,o] + cc[b,n,o]) -------
__global__ __launch_bounds__(256) void k_phaseB(const float* __restrict__ zs,
    const float* __restrict__ ccv, const int* __restrict__ idxp,
    float* __restrict__ out, int O, int ostride, int ooff){
  int t = threadIdx.x;
  int lane = t & 63, w = t >> 6;
  int gn = blockIdx.x*4 + w;
  int b = gn >> 10;
  int mm[KNN];
  const int* ip = idxp + (size_t)gn*KNN;
  #pragma unroll
  for (int k = 0; k < KNN; ++k) mm[k] = ip[k];
  for (int o = lane; o < O; o += 64){
    float cvv = ccv[(size_t)gn*O + o];
    float mx = -INFINITY;
    #pragma unroll 4
    for (int k = 0; k < KNN; ++k){
      float v = leakyf(zs[((size_t)(b*ND) + mm[k])*O + o] + cvv);
      mx = fmaxf(mx, v);
    }
    out[(size_t)gn*ostride + ooff + o] = mx;
  }
}

// ---------------- generic transpose W(O,Cin) -> WT(Cin,O) ----------------
__global__ __launch_bounds__(256) void k_transw(const float* __restrict__ Wsrc,
                                                float* __restrict__ WT, int O, int Cin){
  int i = blockIdx.x*256 + threadIdx.x;
  if (i >= O*Cin) return;
  int o = i / Cin, c = i % Cin;
  WT[(size_t)c*O + o] = Wsrc[i];
}

// ---------------- generic linear: out[bn,o] = in[bn,:].WT[:,o] + bias[o] ----------------
__global__ __launch_bounds__(256) void k_lin(const float* __restrict__ in,
    const float* __restrict__ WT, const float* __restrict__ bias,
    float* __restrict__ out, int Cin, int O){
  int gid = blockIdx.x*256 + threadIdx.x;
  if (gid >= BD*ND*O) return;
  int o = gid % O; int bn = gid / O;
  const float* ip = in + (size_t)bn*Cin;
  float s = bias[o];
  for (int c = 0; c < Cin; ++c) s = fmaf(ip[c], WT[(size_t)c*O + o], s);
  out[gid] = s;
}

// ---------------- flash attention, d=8, heads=8; K,V in LDS per (b,h) ----------------
__global__ __launch_bounds__(256) void k_attn(const float* __restrict__ qkv,
                                              float* __restrict__ outp){
  __shared__ __align__(16) float Ks[ND*8];
  __shared__ __align__(16) float Vs[ND*8];
  int blk = blockIdx.x;
  int chunk = blk & 3; int h = (blk >> 2) & 7; int b = blk >> 5;
  int t = threadIdx.x;
  for (int i = t; i < ND*8; i += 256){
    int m = i >> 3, dd = i & 7;
    size_t base = ((size_t)b*ND + m)*192 + h*8 + dd;
    Ks[i] = qkv[base + 64];
    Vs[i] = qkv[base + 128];
  }
  __syncthreads();
  int n = chunk*256 + t;
  float q[8];
  size_t qb = ((size_t)b*ND + n)*192 + h*8;
  #pragma unroll
  for (int dd = 0; dd < 8; ++dd) q[dd] = qkv[qb + dd];
  const float scale = 0.35355339059327373f;
  float mr = -INFINITY, l = 0.f;
  float acc[8] = {};
  for (int m = 0; m < ND; ++m){
    const float* kr = &Ks[m*8];
    float s = 0.f;
    #pragma unroll
    for (int dd = 0; dd < 8; ++dd) s = fmaf(q[dd], kr[dd], s);
    s *= scale;
    float nm = fmaxf(mr, s);
    float corr = __expf(mr - nm);
    float p = __expf(s - nm);
    l = l*corr + p;
    const float* vr = &Vs[m*8];
    #pragma unroll
    for (int dd = 0; dd < 8; ++dd) acc[dd] = fmaf(p, vr[dd], acc[dd]*corr);
    mr = nm;
  }
  float inv = 1.f/l;
  size_t ob = ((size_t)b*ND + n)*64 + h*8;
  #pragma unroll
  for (int dd = 0; dd < 8; ++dd) outp[ob + dd] = acc[dd]*inv;
}

// ---------------- out-proj + pair-mean: emb[bn,f] = 0.5*(proj[2f]+proj[2f+1]) --------
__global__ __launch_bounds__(256) void k_projmean(const float* __restrict__ attno,
    const float* __restrict__ WoT, const float* __restrict__ bo,
    float* __restrict__ emb){
  int gid = blockIdx.x*256 + threadIdx.x;
  if (gid >= BD*ND*32) return;
  int f = gid % 32; int bn = gid / 32;
  const float* ip = attno + (size_t)bn*64;
  int o0 = 2*f, o1 = 2*f + 1;
  float s0 = bo[o0], s1 = bo[o1];
  for (int c = 0; c < 64; ++c){
    float v = ip[c];
    s0 = fmaf(v, WoT[c*64 + o0], s0);
    s1 = fmaf(v, WoT[c*64 + o1], s1);
  }
  emb[gid] = 0.5f*(s0 + s1);
}

// ---------------- g[b,:] = tanh(mean_n(emb) @ att_w) ----------------
__global__ __launch_bounds__(256) void k_gvec(const float* __restrict__ emb,
    const float* __restrict__ attw, float* __restrict__ g){
  __shared__ float part[8][32];
  __shared__ float meanv[32];
  int b = blockIdx.x, t = threadIdx.x;
  int f = t & 31, j = t >> 5;
  float s = 0.f;
  for (int n = j; n < ND; n += 8) s += emb[((size_t)b*ND + n)*32 + f];
  part[j][f] = s;
  __syncthreads();
  if (t < 32){
    float m = 0.f;
    for (int j2 = 0; j2 < 8; ++j2) m += part[j2][t];
    meanv[t] = m * (1.f/ND);
  }
  __syncthreads();
  if (t < 32){
    float acc = 0.f;
    for (int f2 = 0; f2 < 32; ++f2) acc = fmaf(meanv[f2], attw[f2*32 + t], acc);
    g[b*32 + t] = tanhf(acc);
  }
}

// ---------------- scores[b,n] = sigmoid(emb[b,n,:] . g[b,:]) ----------------
__global__ __launch_bounds__(256) void k_scores(const float* __restrict__ emb,
    const float* __restrict__ g, float* __restrict__ sout){
  int gid = blockIdx.x*256 + threadIdx.x;
  if (gid >= BD*ND) return;
  int b = gid >> 10;
  const float* ep = emb + (size_t)gid*32;
  const float* gp = g + b*32;
  float s = 0.f;
  #pragma unroll
  for (int f = 0; f < 32; ++f) s = fmaf(ep[f], gp[f], s);
  sout[gid] = 1.f/(1.f + __expf(-s));
}

// ---------------- pooled[b,f] = sum_n emb[b,n,f]*s[b,n] ----------------
__global__ __launch_bounds__(256) void k_pool(const float* __restrict__ emb,
    const float* __restrict__ s, float* __restrict__ pooled){
  __shared__ float part[8][32];
  int b = blockIdx.x, t = threadIdx.x;
  int f = t & 31, j = t >> 5;
  float acc = 0.f;
  for (int n = j; n < ND; n += 8)
    acc = fmaf(emb[((size_t)b*ND + n)*32 + f], s[b*ND + n], acc);
  part[j][f] = acc;
  __syncthreads();
  if (t < 32){
    float m = 0.f;
    for (int j2 = 0; j2 < 8; ++j2) m += part[j2][t];
    pooled[b*32 + t] = m;
  }
}

// ---------------- NTN head ----------------
__global__ __launch_bounds__(256) void k_head(const float* __restrict__ p1,
    const float* __restrict__ p2, const float* __restrict__ ntnw,
    const float* __restrict__ ntnv, const float* __restrict__ ntnb,
    const float* __restrict__ fc1w, const float* __restrict__ fc1b,
    const float* __restrict__ scw, const float* __restrict__ scb,
    float* __restrict__ outscore){
  __shared__ float ds[8][32];
  __shared__ float tv[8][16];
  __shared__ float hv[8][16];
  int t = threadIdx.x;
  {
    int b = t >> 5, f = t & 31;
    ds[b][f] = p1[b*32+f] - p2[b*32+f];
  }
  __syncthreads();
  if (t < 128){
    int b = t >> 4, tt = t & 15;
    float acc = ntnb[tt];
    for (int f = 0; f < 32; ++f){
      float df = ds[b][f];
      for (int gg = 0; gg < 32; ++gg)
        acc = fmaf(df*ds[b][gg], ntnw[(f*32+gg)*16 + tt], acc);
    }
    for (int gg = 0; gg < 32; ++gg) acc = fmaf(ds[b][gg], ntnv[tt*32+gg], acc);
    tv[b][tt] = fmaxf(acc, 0.f);
  }
  __syncthreads();
  if (t < 128){
    int b = t >> 4, i = t & 15;
    float acc = fc1b[i];
    for (int kk = 0; kk < 16; ++kk) acc = fmaf(tv[b][kk], fc1w[i*16+kk], acc);
    hv[b][i] = fmaxf(acc, 0.f);
  }
  __syncthreads();
  if (t < 8){
    float acc = scb[0];
    for (int i = 0; i < 16; ++i) acc = fmaf(hv[t][i], scw[i], acc);
    outscore[t] = 1.f/(1.f + __expf(-acc));
  }
}

// =====================================================================================
extern "C" void kernel_launch(void* const* d_in, const int* in_sizes, int n_in,
                              void* d_out, int out_size, void* d_ws, size_t ws_size,
                              hipStream_t stream) {
  auto F = [&](int i){ return (const float*)d_in[i]; };
  const float* feats[2] = { F(0), F(1) };
  const float* cw[3] = { F(2), F(6), F(10) };
  const float* cb[3] = { F(3), F(7), F(11) };
  const float* cg[3] = { F(4), F(8), F(12) };
  const float* cB[3] = { F(5), F(9), F(13) };
  const float* sw[3] = { F(14), F(18), F(22) };
  const float* sb[3] = { F(15), F(19), F(23) };
  const float* sg[3] = { F(16), F(20), F(24) };
  const float* sB[3] = { F(17), F(21), F(25) };
  const float* mha_wi = F(26); const float* mha_bi = F(27);
  const float* mha_wo = F(28); const float* mha_bo = F(29);
  const float* att_w  = F(30);
  const float* ntn_w  = F(31); const float* ntn_v = F(32); const float* ntn_b = F(33);
  const float* fc1_w  = F(34); const float* fc1_b = F(35);
  const float* sc_w   = F(36); const float* sc_b  = F(37);
  float* out = (float*)d_out;

  char* ws = (char*)d_ws;
  // negdist region (33.6 MB), unioned with MHA scratch (never live simultaneously)
  float* nd    = (float*)ws;
  float* qkv   = (float*)ws;                              // 6 MB
  float* attno = (float*)(ws + ((size_t)8  << 20));       // 2 MB
  float* WT1   = (float*)(ws + ((size_t)12 << 20));       // Wi^T
  float* WT2   = (float*)(ws + ((size_t)13 << 20));       // Wo^T
  size_t off = 33554432;
  float* xA   = (float*)(ws + off); off += 4194304;
  float* xB   = (float*)(ws + off); off += 4194304;
  float* zs   = (float*)(ws + off); off += 4194304;
  float* cvb  = (float*)(ws + off); off += 4194304;
  int*   idxb = (int*)  (ws + off); off += 655360;
  float* xxb  = (float*)(ws + off); off += 32768;
  float* fuse = (float*)(ws + off); off += 2097152;
  float* emb1 = (float*)(ws + off); off += 1048576;
  float* emb2 = (float*)(ws + off); off += 1048576;
  float* gbuf = (float*)(ws + off); off += 4096;
  float* pool1= (float*)(ws + off); off += 4096;
  float* pool2= (float*)(ws + off); off += 4096;

  auto knn = [&](const float* xin, int C){
    k_xx  <<<BD*ND/256, 256, 0, stream>>>(xin, xxb, C);
    k_gram<<<dim3(16,16,8), 256, 0, stream>>>(xin, xxb, nd, C);
    k_topk<<<BD*ND/4, 256, 0, stream>>>(nd, idxb);
  };
  auto phA = [&](const float* xin, int C, int O, const float* W, const float* bb,
                 const float* gg, const float* be){
    if (O == 64)       k_phaseA<64> <<<BD*ND/32, 256, 0, stream>>>(xin, W, bb, gg, be, zs, cvb, C);
    else if (O == 128) k_phaseA<128><<<BD*ND/32, 256, 0, stream>>>(xin, W, bb, gg, be, zs, cvb, C);
    else               k_phaseA<32> <<<BD*ND/32, 256, 0, stream>>>(xin, W, bb, gg, be, zs, cvb, C);
  };

  for (int br = 0; br < 2; ++br){
    const float* feat = feats[br];
    float* emb    = br ? emb2  : emb1;
    float* sout   = out + 8 + br*(BD*ND);
    float* pooled = br ? pool2 : pool1;
    for (int part = 0; part < 2; ++part){
      int c0 = part ? 3 : 0;
      int C0 = part ? 12 : 3;
      const float* const* Wl = part ? sw : cw;
      const float* const* bl = part ? sb : cb;
      const float* const* gl = part ? sg : cg;
      const float* const* Bl = part ? sB : cB;
      // layer 0: C0 -> 64
      { int elems = BD*ND*C0;
        k_transpose_in<<<(elems+255)/256, 256, 0, stream>>>(feat, xA, c0, C0); }
      knn(xA, C0);
      phA(xA, C0, 64, Wl[0], bl[0], gl[0], Bl[0]);
      k_phaseB<<<BD*ND/4, 256, 0, stream>>>(zs, cvb, idxb, xB, 64, 64, 0);
      // layer 1: 64 -> 128
      knn(xB, 64);
      phA(xB, 64, 128, Wl[1], bl[1], gl[1], Bl[1]);
      k_phaseB<<<BD*ND/4, 256, 0, stream>>>(zs, cvb, idxb, xA, 128, 128, 0);
      // layer 2: 128 -> 32, written into fuse at column offset
      knn(xA, 128);
      phA(xA, 128, 32, Wl[2], bl[2], gl[2], Bl[2]);
      k_phaseB<<<BD*ND/4, 256, 0, stream>>>(zs, cvb, idxb, fuse, 32, 64, part*32);
    }
    // MHA
    k_transw<<<(192*64+255)/256, 256, 0, stream>>>(mha_wi, WT1, 192, 64);
    k_lin<<<(BD*ND*192)/256, 256, 0, stream>>>(fuse, WT1, mha_bi, qkv, 64, 192);
    k_attn<<<BD*8*4, 256, 0, stream>>>(qkv, attno);
    k_transw<<<(64*64+255)/256, 256, 0, stream>>>(mha_wo, WT2, 64, 64);
    k_projmean<<<(BD*ND*32)/256, 256, 0, stream>>>(attno, WT2, mha_bo, emb);
    // attention pool
    k_gvec<<<BD, 256, 0, stream>>>(emb, att_w, gbuf);
    k_scores<<<(BD*ND)/256, 256, 0, stream>>>(emb, gbuf, sout);
    k_pool<<<BD, 256, 0, stream>>>(emb, sout, pooled);
  }
  k_head<<<1, 256, 0, stream>>>(pool1, pool2, ntn_w, ntn_v, ntn_b,
                                fc1_w, fc1_b, sc_w, sc_b, out);
}

// Round 2
// 1667.075 us; speedup vs baseline: 1.0665x; 1.0665x over previous
//
#include <hip/hip_runtime.h>
#include <math.h>

#define BD 8
#define ND 1024
#define KNN 20
#define NEGS 0.2f
#define BNSC 0.99999500003749969482f

__device__ __forceinline__ float leakyf(float y){ return y >= 0.f ? y : NEGS*y; }

// ---------------- layer-0 input slice: x[b,n,c] = feat[b, c0+c, n] ----------------
__global__ __launch_bounds__(256) void k_transpose_in(const float* __restrict__ feat,
                                                      float* __restrict__ x, int c0, int C){
  int i = blockIdx.x*256 + threadIdx.x;
  int total = BD*ND*C;
  if (i >= total) return;
  int c = i % C; int n = (i / C) % ND; int b = i / (C*ND);
  x[i] = feat[((size_t)b*15 + c0 + c)*ND + n];
}

// ---------------- xx[b,n] = sum_c x^2 (layer 0 only) ----------------
__global__ __launch_bounds__(256) void k_xx(const float* __restrict__ x,
                                            float* __restrict__ xx, int C){
  int i = blockIdx.x*256 + threadIdx.x;
  if (i >= BD*ND) return;
  const float* p = x + (size_t)i*C;
  float s = 0.f;
  for (int c = 0; c < C; ++c) s = fmaf(p[c], p[c], s);
  xx[i] = s;
}

// ---------------- negdist[b,n,m] = 2*dot - xx[n] - xx[m]; 64x64 tiles, 4x4/thread ----
__global__ __launch_bounds__(256) void k_gram(const float* __restrict__ x,
                                              const float* __restrict__ xx,
                                              float* __restrict__ nd, int C){
  __shared__ __align__(16) float At[32][68];
  __shared__ __align__(16) float Bt[32][68];
  int b = blockIdx.z;
  int r0 = blockIdx.y*64, c0 = blockIdx.x*64;
  int t = threadIdx.x;
  int tr = t >> 4, tc = t & 15;
  float acc[4][4] = {};
  const float* xb = x + (size_t)b*ND*C;
  for (int cc = 0; cc < C; cc += 32){
    for (int i = t; i < 64*32; i += 256){
      int row = i >> 5, c = i & 31;
      float av = 0.f, bv = 0.f;
      if (cc + c < C){
        av = xb[(size_t)(r0+row)*C + cc + c];
        bv = xb[(size_t)(c0+row)*C + cc + c];
      }
      At[c][row] = av;
      Bt[c][row] = bv;
    }
    __syncthreads();
    #pragma unroll 4
    for (int c = 0; c < 32; ++c){
      float4 a4 = *(const float4*)&At[c][tr*4];
      float4 b4 = *(const float4*)&Bt[c][tc*4];
      acc[0][0]=fmaf(a4.x,b4.x,acc[0][0]); acc[0][1]=fmaf(a4.x,b4.y,acc[0][1]);
      acc[0][2]=fmaf(a4.x,b4.z,acc[0][2]); acc[0][3]=fmaf(a4.x,b4.w,acc[0][3]);
      acc[1][0]=fmaf(a4.y,b4.x,acc[1][0]); acc[1][1]=fmaf(a4.y,b4.y,acc[1][1]);
      acc[1][2]=fmaf(a4.y,b4.z,acc[1][2]); acc[1][3]=fmaf(a4.y,b4.w,acc[1][3]);
      acc[2][0]=fmaf(a4.z,b4.x,acc[2][0]); acc[2][1]=fmaf(a4.z,b4.y,acc[2][1]);
      acc[2][2]=fmaf(a4.z,b4.z,acc[2][2]); acc[2][3]=fmaf(a4.z,b4.w,acc[2][3]);
      acc[3][0]=fmaf(a4.w,b4.x,acc[3][0]); acc[3][1]=fmaf(a4.w,b4.y,acc[3][1]);
      acc[3][2]=fmaf(a4.w,b4.z,acc[3][2]); acc[3][3]=fmaf(a4.w,b4.w,acc[3][3]);
    }
    __syncthreads();
  }
  float xr[4], xm[4];
  #pragma unroll
  for (int i = 0; i < 4; ++i) xr[i] = xx[b*ND + r0 + tr*4 + i];
  #pragma unroll
  for (int j = 0; j < 4; ++j) xm[j] = xx[b*ND + c0 + tc*4 + j];
  #pragma unroll
  for (int i = 0; i < 4; ++i){
    float4 st;
    st.x = 2.f*acc[i][0] - xr[i] - xm[0];
    st.y = 2.f*acc[i][1] - xr[i] - xm[1];
    st.z = 2.f*acc[i][2] - xr[i] - xm[2];
    st.w = 2.f*acc[i][3] - xr[i] - xm[3];
    *(float4*)&nd[((size_t)b*ND + r0 + tr*4 + i)*ND + c0 + tc*4] = st;
  }
}

// ---------------- top-20 per row; one wave per row, regs only ----------------
__global__ __launch_bounds__(256) void k_topk(const float* __restrict__ nd,
                                              int* __restrict__ idxp){
  int t = threadIdx.x;
  int lane = t & 63, w = t >> 6;
  int rid = blockIdx.x*4 + w;
  const float* src = nd + (size_t)rid*ND;
  float vals[16];
  #pragma unroll
  for (int q = 0; q < 16; ++q) vals[q] = src[q*64 + lane];
  int* op = idxp + (size_t)rid*KNN;
  for (int kk = 0; kk < KNN; ++kk){
    float bv = -INFINITY; int bi = 0x7fffffff;
    #pragma unroll
    for (int q = 0; q < 16; ++q){
      if (vals[q] > bv){ bv = vals[q]; bi = q*64 + lane; }
    }
    #pragma unroll
    for (int off = 32; off; off >>= 1){
      float ov = __shfl_down(bv, off);
      int   oi = __shfl_down(bi, off);
      if (ov > bv || (ov == bv && oi < bi)){ bv = ov; bi = oi; }
    }
    bi = __shfl(bi, 0);
    if (lane == 0) op[kk] = bi;
    #pragma unroll
    for (int q = 0; q < 16; ++q) if (q*64 + lane == bi) vals[q] = -INFINITY;
  }
}

// ------ phase A (register-blocked): zs=alpha*W1.x ; cc=(dW.x+bias)*alpha+beta --------
template<int O>
__global__ __launch_bounds__(256) void k_phaseA(const float* __restrict__ x,
    const float* __restrict__ W, const float* __restrict__ bias,
    const float* __restrict__ gamma, const float* __restrict__ beta,
    float* __restrict__ zs, float* __restrict__ ccv, int C){
  constexpr int TO = O/16;
  constexpr int WP = O + 4;
  __shared__ float W1s[32*WP];
  __shared__ float dWs[32*WP];
  __shared__ float Xs[32*33];
  int blk = blockIdx.x;
  int b = blk >> 5, n0 = (blk & 31)*32;
  int t = threadIdx.x;
  int ot = t & 15, nt = t >> 4;
  int obase = ot*TO;
  int nl = nt*2;
  float az[TO][2] = {}, ac[TO][2] = {};
  for (int cc = 0; cc < C; cc += 32){
    int KC = (C - cc < 32) ? (C - cc) : 32;
    for (int i = t; i < O*KC; i += 256){
      int o = i % O, c = i / O;
      float w1 = W[(size_t)o*2*C + cc + c];
      float w2 = W[(size_t)o*2*C + C + cc + c];
      W1s[c*WP + o] = w1;
      dWs[c*WP + o] = w2 - w1;
    }
    for (int i = t; i < 32*KC; i += 256){
      int c = i % KC, row = i / KC;
      Xs[c*33 + row] = x[((size_t)b*ND + n0 + row)*C + cc + c];
    }
    __syncthreads();
    for (int c = 0; c < KC; ++c){
      float xv0 = Xs[c*33 + nl];
      float xv1 = Xs[c*33 + nl + 1];
      #pragma unroll
      for (int i = 0; i < TO; ++i){
        float w1 = W1s[c*WP + obase + i];
        float dw = dWs[c*WP + obase + i];
        az[i][0] = fmaf(w1, xv0, az[i][0]);
        az[i][1] = fmaf(w1, xv1, az[i][1]);
        ac[i][0] = fmaf(dw, xv0, ac[i][0]);
        ac[i][1] = fmaf(dw, xv1, ac[i][1]);
      }
    }
    __syncthreads();
  }
  #pragma unroll
  for (int i = 0; i < TO; ++i){
    int o = obase + i;
    float alpha = gamma[o]*BNSC;
    float bb = bias[o], be = beta[o];
    #pragma unroll
    for (int q = 0; q < 2; ++q){
      int n = n0 + nl + q;
      size_t off = ((size_t)b*ND + n)*O + o;
      zs[off]  = az[i][q]*alpha;
      ccv[off] = fmaf(ac[i][q] + bb, alpha, be);
    }
  }
}

// ------ phase B: out[b,n,o] = max_k leaky(zs[b,idx_k,o]+cc[b,n,o]); optional xx ------
template<bool DOXX>
__global__ __launch_bounds__(256) void k_phaseB(const float* __restrict__ zs,
    const float* __restrict__ ccv, const int* __restrict__ idxp,
    float* __restrict__ outp, float* __restrict__ xxout,
    int O, int ostride, int ooff){
  int t = threadIdx.x;
  int lane = t & 63, w = t >> 6;
  int gn = blockIdx.x*4 + w;
  int b = gn >> 10;
  int mm[KNN];
  const int* ip = idxp + (size_t)gn*KNN;
  #pragma unroll
  for (int k = 0; k < KNN; ++k) mm[k] = ip[k];
  float sq = 0.f;
  for (int o = lane; o < O; o += 64){
    float cvv = ccv[(size_t)gn*O + o];
    float mx = -INFINITY;
    #pragma unroll 4
    for (int k = 0; k < KNN; ++k){
      float v = leakyf(zs[((size_t)(b*ND) + mm[k])*O + o] + cvv);
      mx = fmaxf(mx, v);
    }
    outp[(size_t)gn*ostride + ooff + o] = mx;
    if (DOXX) sq = fmaf(mx, mx, sq);
  }
  if (DOXX){
    #pragma unroll
    for (int off = 32; off; off >>= 1) sq += __shfl_down(sq, off);
    if (lane == 0) xxout[gn] = sq;
  }
}

// ---------------- qkv[bn,o] = fuse[bn,:].Wi[o,:] + bi[o]  (raw Wi, float4) -----------
__global__ __launch_bounds__(256) void k_lin(const float* __restrict__ in,
    const float* __restrict__ Wm, const float* __restrict__ bias,
    float* __restrict__ outp){
  int gid = blockIdx.x*256 + threadIdx.x;
  if (gid >= BD*ND*192) return;
  int o = gid % 192; int bn = gid / 192;
  const float4* ip = (const float4*)(in + (size_t)bn*64);
  const float4* wp = (const float4*)(Wm + (size_t)o*64);
  float s = bias[o];
  #pragma unroll
  for (int c = 0; c < 16; ++c){
    float4 a = ip[c], wv = wp[c];
    s = fmaf(a.x, wv.x, s); s = fmaf(a.y, wv.y, s);
    s = fmaf(a.z, wv.z, s); s = fmaf(a.w, wv.w, s);
  }
  outp[gid] = s;
}

// ---------------- flash attention, d=8, heads=8; K,V in LDS per (b,h) ----------------
__global__ __launch_bounds__(256) void k_attn(const float* __restrict__ qkv,
                                              float* __restrict__ outp){
  __shared__ __align__(16) float Ks[ND*8];
  __shared__ __align__(16) float Vs[ND*8];
  int blk = blockIdx.x;
  int chunk = blk & 3; int h = (blk >> 2) & 7; int b = blk >> 5;
  int t = threadIdx.x;
  for (int i = t; i < ND*8; i += 256){
    int m = i >> 3, dd = i & 7;
    size_t base = ((size_t)b*ND + m)*192 + h*8 + dd;
    Ks[i] = qkv[base + 64];
    Vs[i] = qkv[base + 128];
  }
  __syncthreads();
  int n = chunk*256 + t;
  float q[8];
  size_t qb = ((size_t)b*ND + n)*192 + h*8;
  #pragma unroll
  for (int dd = 0; dd < 8; ++dd) q[dd] = qkv[qb + dd];
  const float scale = 0.35355339059327373f;
  float mr = -INFINITY, l = 0.f;
  float acc[8] = {};
  for (int m = 0; m < ND; ++m){
    const float* kr = &Ks[m*8];
    float s = 0.f;
    #pragma unroll
    for (int dd = 0; dd < 8; ++dd) s = fmaf(q[dd], kr[dd], s);
    s *= scale;
    float nm = fmaxf(mr, s);
    float corr = __expf(mr - nm);
    float p = __expf(s - nm);
    l = l*corr + p;
    const float* vr = &Vs[m*8];
    #pragma unroll
    for (int dd = 0; dd < 8; ++dd) acc[dd] = fmaf(p, vr[dd], acc[dd]*corr);
    mr = nm;
  }
  float inv = 1.f/l;
  size_t ob = ((size_t)b*ND + n)*64 + h*8;
  #pragma unroll
  for (int dd = 0; dd < 8; ++dd) outp[ob + dd] = acc[dd]*inv;
}

// ------- out-proj + pair-mean: emb[bn,f] = 0.5*(proj[2f]+proj[2f+1]) (raw Wo) --------
__global__ __launch_bounds__(256) void k_projmean(const float* __restrict__ attno,
    const float* __restrict__ Wo, const float* __restrict__ bo,
    float* __restrict__ emb){
  int gid = blockIdx.x*256 + threadIdx.x;
  if (gid >= BD*ND*32) return;
  int f = gid % 32; int bn = gid / 32;
  const float4* ip = (const float4*)(attno + (size_t)bn*64);
  int o0 = 2*f, o1 = 2*f + 1;
  const float4* w0 = (const float4*)(Wo + (size_t)o0*64);
  const float4* w1 = (const float4*)(Wo + (size_t)o1*64);
  float s0 = bo[o0], s1 = bo[o1];
  #pragma unroll
  for (int c = 0; c < 16; ++c){
    float4 a = ip[c], u = w0[c], v = w1[c];
    s0 = fmaf(a.x,u.x,s0); s0 = fmaf(a.y,u.y,s0); s0 = fmaf(a.z,u.z,s0); s0 = fmaf(a.w,u.w,s0);
    s1 = fmaf(a.x,v.x,s1); s1 = fmaf(a.y,v.y,s1); s1 = fmaf(a.z,v.z,s1); s1 = fmaf(a.w,v.w,s1);
  }
  emb[gid] = 0.5f*(s0 + s1);
}

// ---------------- fused attention pool: g, scores, pooled (one block per b) ----------
__global__ __launch_bounds__(256) void k_poolfuse(const float* __restrict__ emb,
    const float* __restrict__ attw, float* __restrict__ sout,
    float* __restrict__ pooled){
  __shared__ float part[8][32];
  __shared__ float meanv[32];
  __shared__ float gv[32];
  __shared__ float sc[ND];
  int b = blockIdx.x, t = threadIdx.x;
  int f = t & 31, j = t >> 5;
  const float* eb = emb + (size_t)b*ND*32;
  float s = 0.f;
  for (int n = j; n < ND; n += 8) s += eb[n*32 + f];
  part[j][f] = s;
  __syncthreads();
  if (t < 32){
    float m = 0.f;
    for (int j2 = 0; j2 < 8; ++j2) m += part[j2][t];
    meanv[t] = m * (1.f/ND);
  }
  __syncthreads();
  if (t < 32){
    float acc = 0.f;
    for (int f2 = 0; f2 < 32; ++f2) acc = fmaf(meanv[f2], attw[f2*32 + t], acc);
    gv[t] = tanhf(acc);
  }
  __syncthreads();
  for (int n = t; n < ND; n += 256){
    const float4* ep = (const float4*)(eb + n*32);
    float acc = 0.f;
    #pragma unroll
    for (int f4 = 0; f4 < 8; ++f4){
      float4 e = ep[f4];
      acc = fmaf(e.x, gv[f4*4+0], acc);
      acc = fmaf(e.y, gv[f4*4+1], acc);
      acc = fmaf(e.z, gv[f4*4+2], acc);
      acc = fmaf(e.w, gv[f4*4+3], acc);
    }
    float sg = 1.f/(1.f + __expf(-acc));
    sout[b*ND + n] = sg;
    sc[n] = sg;
  }
  __syncthreads();
  float pacc = 0.f;
  for (int n = j; n < ND; n += 8) pacc = fmaf(eb[n*32 + f], sc[n], pacc);
  part[j][f] = pacc;
  __syncthreads();
  if (t < 32){
    float m = 0.f;
    for (int j2 = 0; j2 < 8; ++j2) m += part[j2][t];
    pooled[b*32 + t] = m;
  }
}

// ---------------- NTN head: LDS-staged weights (2-phase, 32KB each) ----------------
__global__ __launch_bounds__(256) void k_head(const float* __restrict__ p1,
    const float* __restrict__ p2, const float* __restrict__ ntnw,
    const float* __restrict__ ntnv, const float* __restrict__ ntnb,
    const float* __restrict__ fc1w, const float* __restrict__ fc1b,
    const float* __restrict__ scw, const float* __restrict__ scb,
    float* __restrict__ outscore){
  __shared__ __align__(16) float Wl[8192];
  __shared__ float Vl[512];
  __shared__ float F1[256];
  __shared__ float ds[8][32];
  __shared__ float tv[8][16];
  __shared__ float hv[8][16];
  int t = threadIdx.x;
  {
    int b = t >> 5, f = t & 31;
    ds[b][f] = p1[b*32+f] - p2[b*32+f];
  }
  for (int i = t; i < 512; i += 256) Vl[i] = ntnv[i];
  if (t < 256) F1[t] = fc1w[t];
  float acc = 0.f;
  for (int ph = 0; ph < 2; ++ph){
    __syncthreads();
    {
      const float4* src = (const float4*)(ntnw + ph*8192);
      float4* dst = (float4*)Wl;
      for (int i = t; i < 2048; i += 256) dst[i] = src[i];
    }
    __syncthreads();
    if (t < 128){
      int b = t >> 4, tt = t & 15;
      for (int fi = 0; fi < 16; ++fi){
        float df = ds[b][ph*16 + fi];
        #pragma unroll 8
        for (int gg = 0; gg < 32; ++gg)
          acc = fmaf(df*ds[b][gg], Wl[(fi*32+gg)*16 + tt], acc);
      }
    }
  }
  if (t < 128){
    int b = t >> 4, tt = t & 15;
    acc += ntnb[tt];
    for (int gg = 0; gg < 32; ++gg) acc = fmaf(ds[b][gg], Vl[tt*32+gg], acc);
    tv[b][tt] = fmaxf(acc, 0.f);
  }
  __syncthreads();
  if (t < 128){
    int b = t >> 4, i = t & 15;
    float a2 = fc1b[i];
    for (int kk = 0; kk < 16; ++kk) a2 = fmaf(tv[b][kk], F1[i*16+kk], a2);
    hv[b][i] = fmaxf(a2, 0.f);
  }
  __syncthreads();
  if (t < 8){
    float a3 = scb[0];
    for (int i = 0; i < 16; ++i) a3 = fmaf(hv[t][i], scw[i], a3);
    outscore[t] = 1.f/(1.f + __expf(-a3));
  }
}

// =====================================================================================
extern "C" void kernel_launch(void* const* d_in, const int* in_sizes, int n_in,
                              void* d_out, int out_size, void* d_ws, size_t ws_size,
                              hipStream_t stream) {
  auto F = [&](int i){ return (const float*)d_in[i]; };
  const float* feats[2] = { F(0), F(1) };
  const float* cw[3] = { F(2), F(6), F(10) };
  const float* cb[3] = { F(3), F(7), F(11) };
  const float* cg[3] = { F(4), F(8), F(12) };
  const float* cB[3] = { F(5), F(9), F(13) };
  const float* sw[3] = { F(14), F(18), F(22) };
  const float* sb[3] = { F(15), F(19), F(23) };
  const float* sg[3] = { F(16), F(20), F(24) };
  const float* sB[3] = { F(17), F(21), F(25) };
  const float* mha_wi = F(26); const float* mha_bi = F(27);
  const float* mha_wo = F(28); const float* mha_bo = F(29);
  const float* att_w  = F(30);
  const float* ntn_w  = F(31); const float* ntn_v = F(32); const float* ntn_b = F(33);
  const float* fc1_w  = F(34); const float* fc1_b = F(35);
  const float* sc_w   = F(36); const float* sc_b  = F(37);
  float* out = (float*)d_out;

  char* ws = (char*)d_ws;
  // negdist region (33.6 MB), unioned with MHA scratch (never live simultaneously)
  float* nd    = (float*)ws;
  float* qkv   = (float*)ws;                              // 6 MB
  float* attno = (float*)(ws + ((size_t)8  << 20));       // 2 MB
  size_t off = 33554432;
  float* xA   = (float*)(ws + off); off += 4194304;
  float* xB   = (float*)(ws + off); off += 4194304;
  float* zs   = (float*)(ws + off); off += 4194304;
  float* cvb  = (float*)(ws + off); off += 4194304;
  int*   idxb = (int*)  (ws + off); off += 655360;
  float* xxb  = (float*)(ws + off); off += 32768;
  float* fuse = (float*)(ws + off); off += 2097152;
  float* emb1 = (float*)(ws + off); off += 1048576;
  float* emb2 = (float*)(ws + off); off += 1048576;
  float* pool1= (float*)(ws + off); off += 4096;
  float* pool2= (float*)(ws + off); off += 4096;

  auto knn = [&](const float* xin, int C){
    k_gram<<<dim3(16,16,8), 256, 0, stream>>>(xin, xxb, nd, C);
    k_topk<<<BD*ND/4, 256, 0, stream>>>(nd, idxb);
  };
  auto phA = [&](const float* xin, int C, int O, const float* W, const float* bb,
                 const float* gg, const float* be){
    if (O == 64)       k_phaseA<64> <<<BD*ND/32, 256, 0, stream>>>(xin, W, bb, gg, be, zs, cvb, C);
    else if (O == 128) k_phaseA<128><<<BD*ND/32, 256, 0, stream>>>(xin, W, bb, gg, be, zs, cvb, C);
    else               k_phaseA<32> <<<BD*ND/32, 256, 0, stream>>>(xin, W, bb, gg, be, zs, cvb, C);
  };

  for (int br = 0; br < 2; ++br){
    const float* feat = feats[br];
    float* emb    = br ? emb2  : emb1;
    float* sout   = out + 8 + br*(BD*ND);
    float* pooled = br ? pool2 : pool1;
    for (int part = 0; part < 2; ++part){
      int c0 = part ? 3 : 0;
      int C0 = part ? 12 : 3;
      const float* const* Wl = part ? sw : cw;
      const float* const* bl = part ? sb : cb;
      const float* const* gl = part ? sg : cg;
      const float* const* Bl = part ? sB : cB;
      // layer 0: C0 -> 64
      { int elems = BD*ND*C0;
        k_transpose_in<<<(elems+255)/256, 256, 0, stream>>>(feat, xA, c0, C0); }
      k_xx<<<BD*ND/256, 256, 0, stream>>>(xA, xxb, C0);
      knn(xA, C0);
      phA(xA, C0, 64, Wl[0], bl[0], gl[0], Bl[0]);
      k_phaseB<true><<<BD*ND/4, 256, 0, stream>>>(zs, cvb, idxb, xB, xxb, 64, 64, 0);
      // layer 1: 64 -> 128 (xx already produced by phaseB)
      knn(xB, 64);
      phA(xB, 64, 128, Wl[1], bl[1], gl[1], Bl[1]);
      k_phaseB<true><<<BD*ND/4, 256, 0, stream>>>(zs, cvb, idxb, xA, xxb, 128, 128, 0);
      // layer 2: 128 -> 32, written into fuse at column offset
      knn(xA, 128);
      phA(xA, 128, 32, Wl[2], bl[2], gl[2], Bl[2]);
      k_phaseB<false><<<BD*ND/4, 256, 0, stream>>>(zs, cvb, idxb, fuse, nullptr, 32, 64, part*32);
    }
    // MHA
    k_lin<<<(BD*ND*192)/256, 256, 0, stream>>>(fuse, mha_wi, mha_bi, qkv);
    k_attn<<<BD*8*4, 256, 0, stream>>>(qkv, attno);
    k_projmean<<<(BD*ND*32)/256, 256, 0, stream>>>(attno, mha_wo, mha_bo, emb);
    // fused attention pool
    k_poolfuse<<<BD, 256, 0, stream>>>(emb, att_w, sout, pooled);
  }
  k_head<<<1, 256, 0, stream>>>(pool1, pool2, ntn_w, ntn_v, ntn_b,
                                fc1_w, fc1_b, sc_w, sc_b, out);
}

// Round 3
// 1612.707 us; speedup vs baseline: 1.1024x; 1.0337x over previous
//
#include <hip/hip_runtime.h>
#include <math.h>

#define BD 8
#define ND 1024
#define KNN 20
#define NEGS 0.2f
#define BNSC 0.99999500003749969482f
#define KSL 8      // key slices for flash-decode attention
#define KPS 128    // keys per slice

__device__ __forceinline__ float leakyf(float y){ return y >= 0.f ? y : NEGS*y; }

// ---------------- layer-0 input slice: x[b,n,c] = feat[b, c0+c, n] ----------------
__global__ __launch_bounds__(256) void k_transpose_in(const float* __restrict__ feat,
                                                      float* __restrict__ x, int c0, int C){
  int i = blockIdx.x*256 + threadIdx.x;
  int total = BD*ND*C;
  if (i >= total) return;
  int c = i % C; int n = (i / C) % ND; int b = i / (C*ND);
  x[i] = feat[((size_t)b*15 + c0 + c)*ND + n];
}

// ---------------- xx[b,n] = sum_c x^2 (layer 0 only) ----------------
__global__ __launch_bounds__(256) void k_xx(const float* __restrict__ x,
                                            float* __restrict__ xx, int C){
  int i = blockIdx.x*256 + threadIdx.x;
  if (i >= BD*ND) return;
  const float* p = x + (size_t)i*C;
  float s = 0.f;
  for (int c = 0; c < C; ++c) s = fmaf(p[c], p[c], s);
  xx[i] = s;
}

// ---------------- negdist[b,n,m] = 2*dot - xx[n] - xx[m]; 64x64 tiles, 4x4/thread ----
__global__ __launch_bounds__(256) void k_gram(const float* __restrict__ x,
                                              const float* __restrict__ xx,
                                              float* __restrict__ nd, int C){
  __shared__ __align__(16) float At[32][68];
  __shared__ __align__(16) float Bt[32][68];
  int b = blockIdx.z;
  int r0 = blockIdx.y*64, c0 = blockIdx.x*64;
  int t = threadIdx.x;
  int tr = t >> 4, tc = t & 15;
  float acc[4][4] = {};
  const float* xb = x + (size_t)b*ND*C;
  for (int cc = 0; cc < C; cc += 32){
    for (int i = t; i < 64*32; i += 256){
      int row = i >> 5, c = i & 31;
      float av = 0.f, bv = 0.f;
      if (cc + c < C){
        av = xb[(size_t)(r0+row)*C + cc + c];
        bv = xb[(size_t)(c0+row)*C + cc + c];
      }
      At[c][row] = av;
      Bt[c][row] = bv;
    }
    __syncthreads();
    #pragma unroll 4
    for (int c = 0; c < 32; ++c){
      float4 a4 = *(const float4*)&At[c][tr*4];
      float4 b4 = *(const float4*)&Bt[c][tc*4];
      acc[0][0]=fmaf(a4.x,b4.x,acc[0][0]); acc[0][1]=fmaf(a4.x,b4.y,acc[0][1]);
      acc[0][2]=fmaf(a4.x,b4.z,acc[0][2]); acc[0][3]=fmaf(a4.x,b4.w,acc[0][3]);
      acc[1][0]=fmaf(a4.y,b4.x,acc[1][0]); acc[1][1]=fmaf(a4.y,b4.y,acc[1][1]);
      acc[1][2]=fmaf(a4.y,b4.z,acc[1][2]); acc[1][3]=fmaf(a4.y,b4.w,acc[1][3]);
      acc[2][0]=fmaf(a4.z,b4.x,acc[2][0]); acc[2][1]=fmaf(a4.z,b4.y,acc[2][1]);
      acc[2][2]=fmaf(a4.z,b4.z,acc[2][2]); acc[2][3]=fmaf(a4.z,b4.w,acc[2][3]);
      acc[3][0]=fmaf(a4.w,b4.x,acc[3][0]); acc[3][1]=fmaf(a4.w,b4.y,acc[3][1]);
      acc[3][2]=fmaf(a4.w,b4.z,acc[3][2]); acc[3][3]=fmaf(a4.w,b4.w,acc[3][3]);
    }
    __syncthreads();
  }
  float xr[4], xm[4];
  #pragma unroll
  for (int i = 0; i < 4; ++i) xr[i] = xx[b*ND + r0 + tr*4 + i];
  #pragma unroll
  for (int j = 0; j < 4; ++j) xm[j] = xx[b*ND + c0 + tc*4 + j];
  #pragma unroll
  for (int i = 0; i < 4; ++i){
    float4 st;
    st.x = 2.f*acc[i][0] - xr[i] - xm[0];
    st.y = 2.f*acc[i][1] - xr[i] - xm[1];
    st.z = 2.f*acc[i][2] - xr[i] - xm[2];
    st.w = 2.f*acc[i][3] - xr[i] - xm[3];
    *(float4*)&nd[((size_t)b*ND + r0 + tr*4 + i)*ND + c0 + tc*4] = st;
  }
}

// ---------------- top-20 per row; one wave per row, regs only ----------------
__global__ __launch_bounds__(256) void k_topk(const float* __restrict__ nd,
                                              int* __restrict__ idxp){
  int t = threadIdx.x;
  int lane = t & 63, w = t >> 6;
  int rid = blockIdx.x*4 + w;
  const float* src = nd + (size_t)rid*ND;
  float vals[16];
  #pragma unroll
  for (int q = 0; q < 16; ++q) vals[q] = src[q*64 + lane];
  int* op = idxp + (size_t)rid*KNN;
  for (int kk = 0; kk < KNN; ++kk){
    float bv = -INFINITY; int bi = 0x7fffffff;
    #pragma unroll
    for (int q = 0; q < 16; ++q){
      if (vals[q] > bv){ bv = vals[q]; bi = q*64 + lane; }
    }
    #pragma unroll
    for (int off = 32; off; off >>= 1){
      float ov = __shfl_down(bv, off);
      int   oi = __shfl_down(bi, off);
      if (ov > bv || (ov == bv && oi < bi)){ bv = ov; bi = oi; }
    }
    bi = __shfl(bi, 0);
    if (lane == 0) op[kk] = bi;
    #pragma unroll
    for (int q = 0; q < 16; ++q) if (q*64 + lane == bi) vals[q] = -INFINITY;
  }
}

// ------ phase A (register-blocked): zs=alpha*W1.x ; cc=(dW.x+bias)*alpha+beta --------
template<int O>
__global__ __launch_bounds__(256) void k_phaseA(const float* __restrict__ x,
    const float* __restrict__ W, const float* __restrict__ bias,
    const float* __restrict__ gamma, const float* __restrict__ beta,
    float* __restrict__ zs, float* __restrict__ ccv, int C){
  constexpr int TO = O/16;
  constexpr int WP = O + 4;
  __shared__ float W1s[32*WP];
  __shared__ float dWs[32*WP];
  __shared__ float Xs[32*33];
  int blk = blockIdx.x;
  int b = blk >> 5, n0 = (blk & 31)*32;
  int t = threadIdx.x;
  int ot = t & 15, nt = t >> 4;
  int obase = ot*TO;
  int nl = nt*2;
  float az[TO][2] = {}, ac[TO][2] = {};
  for (int cc = 0; cc < C; cc += 32){
    int KC = (C - cc < 32) ? (C - cc) : 32;
    for (int i = t; i < O*KC; i += 256){
      int o = i % O, c = i / O;
      float w1 = W[(size_t)o*2*C + cc + c];
      float w2 = W[(size_t)o*2*C + C + cc + c];
      W1s[c*WP + o] = w1;
      dWs[c*WP + o] = w2 - w1;
    }
    for (int i = t; i < 32*KC; i += 256){
      int c = i % KC, row = i / KC;
      Xs[c*33 + row] = x[((size_t)b*ND + n0 + row)*C + cc + c];
    }
    __syncthreads();
    for (int c = 0; c < KC; ++c){
      float xv0 = Xs[c*33 + nl];
      float xv1 = Xs[c*33 + nl + 1];
      #pragma unroll
      for (int i = 0; i < TO; ++i){
        float w1 = W1s[c*WP + obase + i];
        float dw = dWs[c*WP + obase + i];
        az[i][0] = fmaf(w1, xv0, az[i][0]);
        az[i][1] = fmaf(w1, xv1, az[i][1]);
        ac[i][0] = fmaf(dw, xv0, ac[i][0]);
        ac[i][1] = fmaf(dw, xv1, ac[i][1]);
      }
    }
    __syncthreads();
  }
  #pragma unroll
  for (int i = 0; i < TO; ++i){
    int o = obase + i;
    float alpha = gamma[o]*BNSC;
    float bb = bias[o], be = beta[o];
    #pragma unroll
    for (int q = 0; q < 2; ++q){
      int n = n0 + nl + q;
      size_t off = ((size_t)b*ND + n)*O + o;
      zs[off]  = az[i][q]*alpha;
      ccv[off] = fmaf(ac[i][q] + bb, alpha, be);
    }
  }
}

// ------ phase B: out[b,n,o] = max_k leaky(zs[b,idx_k,o]+cc[b,n,o]); optional xx ------
template<bool DOXX>
__global__ __launch_bounds__(256) void k_phaseB(const float* __restrict__ zs,
    const float* __restrict__ ccv, const int* __restrict__ idxp,
    float* __restrict__ outp, float* __restrict__ xxout,
    int O, int ostride, int ooff){
  int t = threadIdx.x;
  int lane = t & 63, w = t >> 6;
  int gn = blockIdx.x*4 + w;
  int b = gn >> 10;
  int mm[KNN];
  const int* ip = idxp + (size_t)gn*KNN;
  #pragma unroll
  for (int k = 0; k < KNN; ++k) mm[k] = ip[k];
  float sq = 0.f;
  for (int o = lane; o < O; o += 64){
    float cvv = ccv[(size_t)gn*O + o];
    float mx = -INFINITY;
    #pragma unroll 4
    for (int k = 0; k < KNN; ++k){
      float v = leakyf(zs[((size_t)(b*ND) + mm[k])*O + o] + cvv);
      mx = fmaxf(mx, v);
    }
    outp[(size_t)gn*ostride + ooff + o] = mx;
    if (DOXX) sq = fmaf(mx, mx, sq);
  }
  if (DOXX){
    #pragma unroll
    for (int off = 32; off; off >>= 1) sq += __shfl_down(sq, off);
    if (lane == 0) xxout[gn] = sq;
  }
}

// ---------------- qkv[bn,o] = fuse[bn,:].Wi[o,:] + bi[o]  (raw Wi, float4) -----------
__global__ __launch_bounds__(256) void k_lin(const float* __restrict__ in,
    const float* __restrict__ Wm, const float* __restrict__ bias,
    float* __restrict__ outp){
  int gid = blockIdx.x*256 + threadIdx.x;
  if (gid >= BD*ND*192) return;
  int o = gid % 192; int bn = gid / 192;
  const float4* ip = (const float4*)(in + (size_t)bn*64);
  const float4* wp = (const float4*)(Wm + (size_t)o*64);
  float s = bias[o];
  #pragma unroll
  for (int c = 0; c < 16; ++c){
    float4 a = ip[c], wv = wp[c];
    s = fmaf(a.x, wv.x, s); s = fmaf(a.y, wv.y, s);
    s = fmaf(a.z, wv.z, s); s = fmaf(a.w, wv.w, s);
  }
  outp[gid] = s;
}

// ------- flash-decode attention part: K-slice per block, 4 queries/thread ------------
__global__ __launch_bounds__(256) void k_attn_part(const float* __restrict__ qkv,
    float* __restrict__ pm, float* __restrict__ pl, float* __restrict__ pacc){
  __shared__ __align__(16) float Ks[KPS*8];
  __shared__ __align__(16) float Vs[KPS*8];
  int blk = blockIdx.x;                 // 8*8*8 = 512 blocks
  int ksl = blk & 7; int h = (blk >> 3) & 7; int b = blk >> 6;
  int t = threadIdx.x;
  for (int i = t; i < KPS*8; i += 256){
    int m = i >> 3, dd = i & 7;
    size_t base = ((size_t)b*ND + ksl*KPS + m)*192 + h*8 + dd;
    Ks[i] = qkv[base + 64];
    Vs[i] = qkv[base + 128];
  }
  __syncthreads();
  const float scale = 0.35355339059327373f;
  float q[4][8];
  #pragma unroll
  for (int u = 0; u < 4; ++u){
    int n = u*256 + t;
    const float* qp = qkv + ((size_t)b*ND + n)*192 + h*8;
    #pragma unroll
    for (int dd = 0; dd < 8; ++dd) q[u][dd] = qp[dd]*scale;
  }
  float mr[4] = {-INFINITY,-INFINITY,-INFINITY,-INFINITY};
  float l[4] = {};
  float acc[4][8] = {};
  for (int m = 0; m < KPS; ++m){
    float4 k0 = *(const float4*)&Ks[m*8];
    float4 k1 = *(const float4*)&Ks[m*8+4];
    float4 v0 = *(const float4*)&Vs[m*8];
    float4 v1 = *(const float4*)&Vs[m*8+4];
    #pragma unroll
    for (int u = 0; u < 4; ++u){
      float s;
      s = q[u][0]*k0.x;        s = fmaf(q[u][1], k0.y, s);
      s = fmaf(q[u][2], k0.z, s); s = fmaf(q[u][3], k0.w, s);
      s = fmaf(q[u][4], k1.x, s); s = fmaf(q[u][5], k1.y, s);
      s = fmaf(q[u][6], k1.z, s); s = fmaf(q[u][7], k1.w, s);
      float nm = fmaxf(mr[u], s);
      float corr = __expf(mr[u] - nm);
      float p = __expf(s - nm);
      l[u] = fmaf(l[u], corr, p);
      acc[u][0] = fmaf(p, v0.x, acc[u][0]*corr);
      acc[u][1] = fmaf(p, v0.y, acc[u][1]*corr);
      acc[u][2] = fmaf(p, v0.z, acc[u][2]*corr);
      acc[u][3] = fmaf(p, v0.w, acc[u][3]*corr);
      acc[u][4] = fmaf(p, v1.x, acc[u][4]*corr);
      acc[u][5] = fmaf(p, v1.y, acc[u][5]*corr);
      acc[u][6] = fmaf(p, v1.z, acc[u][6]*corr);
      acc[u][7] = fmaf(p, v1.w, acc[u][7]*corr);
      mr[u] = nm;
    }
  }
  #pragma unroll
  for (int u = 0; u < 4; ++u){
    int n = u*256 + t;
    size_t pidx = (((size_t)(b*8 + h))*8 + ksl)*ND + n;
    pm[pidx] = mr[u];
    pl[pidx] = l[u];
    float4* ap = (float4*)&pacc[pidx*8];
    ap[0] = make_float4(acc[u][0], acc[u][1], acc[u][2], acc[u][3]);
    ap[1] = make_float4(acc[u][4], acc[u][5], acc[u][6], acc[u][7]);
  }
}

// ------- flash-decode combine: merge KSL partials per (b,h,n) -----------------------
__global__ __launch_bounds__(256) void k_attn_comb(const float* __restrict__ pm,
    const float* __restrict__ pl, const float* __restrict__ pacc,
    float* __restrict__ attno){
  int gid = blockIdx.x*256 + threadIdx.x;   // (b*8+h)*1024+n, total 65536
  if (gid >= BD*8*ND) return;
  int n = gid & 1023; int bh = gid >> 10;
  int h = bh & 7; int b = bh >> 3;
  float ms[KSL], ls[KSL];
  float M = -INFINITY;
  #pragma unroll
  for (int s = 0; s < KSL; ++s){
    size_t pidx = ((size_t)bh*8 + s)*ND + n;
    ms[s] = pm[pidx]; ls[s] = pl[pidx];
    M = fmaxf(M, ms[s]);
  }
  float L = 0.f;
  float o[8] = {};
  #pragma unroll
  for (int s = 0; s < KSL; ++s){
    float w = __expf(ms[s] - M);
    L = fmaf(ls[s], w, L);
    const float4* ap = (const float4*)&pacc[(((size_t)bh*8 + s)*ND + n)*8];
    float4 a0 = ap[0], a1 = ap[1];
    o[0] = fmaf(w, a0.x, o[0]); o[1] = fmaf(w, a0.y, o[1]);
    o[2] = fmaf(w, a0.z, o[2]); o[3] = fmaf(w, a0.w, o[3]);
    o[4] = fmaf(w, a1.x, o[4]); o[5] = fmaf(w, a1.y, o[5]);
    o[6] = fmaf(w, a1.z, o[6]); o[7] = fmaf(w, a1.w, o[7]);
  }
  float inv = 1.f/L;
  float4* dst = (float4*)&attno[((size_t)b*ND + n)*64 + h*8];
  dst[0] = make_float4(o[0]*inv, o[1]*inv, o[2]*inv, o[3]*inv);
  dst[1] = make_float4(o[4]*inv, o[5]*inv, o[6]*inv, o[7]*inv);
}

// ------- out-proj + pair-mean: emb[bn,f] = 0.5*(proj[2f]+proj[2f+1]) (raw Wo) --------
__global__ __launch_bounds__(256) void k_projmean(const float* __restrict__ attno,
    const float* __restrict__ Wo, const float* __restrict__ bo,
    float* __restrict__ emb){
  int gid = blockIdx.x*256 + threadIdx.x;
  if (gid >= BD*ND*32) return;
  int f = gid % 32; int bn = gid / 32;
  const float4* ip = (const float4*)(attno + (size_t)bn*64);
  int o0 = 2*f, o1 = 2*f + 1;
  const float4* w0 = (const float4*)(Wo + (size_t)o0*64);
  const float4* w1 = (const float4*)(Wo + (size_t)o1*64);
  float s0 = bo[o0], s1 = bo[o1];
  #pragma unroll
  for (int c = 0; c < 16; ++c){
    float4 a = ip[c], u = w0[c], v = w1[c];
    s0 = fmaf(a.x,u.x,s0); s0 = fmaf(a.y,u.y,s0); s0 = fmaf(a.z,u.z,s0); s0 = fmaf(a.w,u.w,s0);
    s1 = fmaf(a.x,v.x,s1); s1 = fmaf(a.y,v.y,s1); s1 = fmaf(a.z,v.z,s1); s1 = fmaf(a.w,v.w,s1);
  }
  emb[gid] = 0.5f*(s0 + s1);
}

// ---------------- fused attention pool: g, scores, pooled (one block per b) ----------
__global__ __launch_bounds__(256) void k_poolfuse(const float* __restrict__ emb,
    const float* __restrict__ attw, float* __restrict__ sout,
    float* __restrict__ pooled){
  __shared__ float part[8][32];
  __shared__ float meanv[32];
  __shared__ float gv[32];
  __shared__ float sc[ND];
  int b = blockIdx.x, t = threadIdx.x;
  int f = t & 31, j = t >> 5;
  const float* eb = emb + (size_t)b*ND*32;
  float s = 0.f;
  for (int n = j; n < ND; n += 8) s += eb[n*32 + f];
  part[j][f] = s;
  __syncthreads();
  if (t < 32){
    float m = 0.f;
    for (int j2 = 0; j2 < 8; ++j2) m += part[j2][t];
    meanv[t] = m * (1.f/ND);
  }
  __syncthreads();
  if (t < 32){
    float acc = 0.f;
    for (int f2 = 0; f2 < 32; ++f2) acc = fmaf(meanv[f2], attw[f2*32 + t], acc);
    gv[t] = tanhf(acc);
  }
  __syncthreads();
  for (int n = t; n < ND; n += 256){
    const float4* ep = (const float4*)(eb + n*32);
    float acc = 0.f;
    #pragma unroll
    for (int f4 = 0; f4 < 8; ++f4){
      float4 e = ep[f4];
      acc = fmaf(e.x, gv[f4*4+0], acc);
      acc = fmaf(e.y, gv[f4*4+1], acc);
      acc = fmaf(e.z, gv[f4*4+2], acc);
      acc = fmaf(e.w, gv[f4*4+3], acc);
    }
    float sg = 1.f/(1.f + __expf(-acc));
    sout[b*ND + n] = sg;
    sc[n] = sg;
  }
  __syncthreads();
  float pacc = 0.f;
  for (int n = j; n < ND; n += 8) pacc = fmaf(eb[n*32 + f], sc[n], pacc);
  part[j][f] = pacc;
  __syncthreads();
  if (t < 32){
    float m = 0.f;
    for (int j2 = 0; j2 < 8; ++j2) m += part[j2][t];
    pooled[b*32 + t] = m;
  }
}

// ---------------- NTN head: LDS-staged weights (2-phase, 32KB each) ----------------
__global__ __launch_bounds__(256) void k_head(const float* __restrict__ p1,
    const float* __restrict__ p2, const float* __restrict__ ntnw,
    const float* __restrict__ ntnv, const float* __restrict__ ntnb,
    const float* __restrict__ fc1w, const float* __restrict__ fc1b,
    const float* __restrict__ scw, const float* __restrict__ scb,
    float* __restrict__ outscore){
  __shared__ __align__(16) float Wl[8192];
  __shared__ float Vl[512];
  __shared__ float F1[256];
  __shared__ float ds[8][32];
  __shared__ float tv[8][16];
  __shared__ float hv[8][16];
  int t = threadIdx.x;
  {
    int b = t >> 5, f = t & 31;
    ds[b][f] = p1[b*32+f] - p2[b*32+f];
  }
  for (int i = t; i < 512; i += 256) Vl[i] = ntnv[i];
  if (t < 256) F1[t] = fc1w[t];
  float acc = 0.f;
  for (int ph = 0; ph < 2; ++ph){
    __syncthreads();
    {
      const float4* src = (const float4*)(ntnw + ph*8192);
      float4* dst = (float4*)Wl;
      for (int i = t; i < 2048; i += 256) dst[i] = src[i];
    }
    __syncthreads();
    if (t < 128){
      int b = t >> 4, tt = t & 15;
      for (int fi = 0; fi < 16; ++fi){
        float df = ds[b][ph*16 + fi];
        #pragma unroll 8
        for (int gg = 0; gg < 32; ++gg)
          acc = fmaf(df*ds[b][gg], Wl[(fi*32+gg)*16 + tt], acc);
      }
    }
  }
  if (t < 128){
    int b = t >> 4, tt = t & 15;
    acc += ntnb[tt];
    for (int gg = 0; gg < 32; ++gg) acc = fmaf(ds[b][gg], Vl[tt*32+gg], acc);
    tv[b][tt] = fmaxf(acc, 0.f);
  }
  __syncthreads();
  if (t < 128){
    int b = t >> 4, i = t & 15;
    float a2 = fc1b[i];
    for (int kk = 0; kk < 16; ++kk) a2 = fmaf(tv[b][kk], F1[i*16+kk], a2);
    hv[b][i] = fmaxf(a2, 0.f);
  }
  __syncthreads();
  if (t < 8){
    float a3 = scb[0];
    for (int i = 0; i < 16; ++i) a3 = fmaf(hv[t][i], scw[i], a3);
    outscore[t] = 1.f/(1.f + __expf(-a3));
  }
}

// =====================================================================================
extern "C" void kernel_launch(void* const* d_in, const int* in_sizes, int n_in,
                              void* d_out, int out_size, void* d_ws, size_t ws_size,
                              hipStream_t stream) {
  auto F = [&](int i){ return (const float*)d_in[i]; };
  const float* feats[2] = { F(0), F(1) };
  const float* cw[3] = { F(2), F(6), F(10) };
  const float* cb[3] = { F(3), F(7), F(11) };
  const float* cg[3] = { F(4), F(8), F(12) };
  const float* cB[3] = { F(5), F(9), F(13) };
  const float* sw[3] = { F(14), F(18), F(22) };
  const float* sb[3] = { F(15), F(19), F(23) };
  const float* sg[3] = { F(16), F(20), F(24) };
  const float* sB[3] = { F(17), F(21), F(25) };
  const float* mha_wi = F(26); const float* mha_bi = F(27);
  const float* mha_wo = F(28); const float* mha_bo = F(29);
  const float* att_w  = F(30);
  const float* ntn_w  = F(31); const float* ntn_v = F(32); const float* ntn_b = F(33);
  const float* fc1_w  = F(34); const float* fc1_b = F(35);
  const float* sc_w   = F(36); const float* sc_b  = F(37);
  float* out = (float*)d_out;

  char* ws = (char*)d_ws;
  // negdist region [0, 32 MiB), unioned with MHA scratch (never live simultaneously)
  float* nd    = (float*)ws;
  float* qkv   = (float*)ws;                              // [0, 6 MiB)
  float* attno = (float*)(ws + ((size_t)8  << 20));       // [8, 10 MiB)
  float* pmb   = (float*)(ws + ((size_t)10 << 20));       // [10, 12 MiB)
  float* plb   = (float*)(ws + ((size_t)12 << 20));       // [12, 14 MiB)
  float* paccb = (float*)(ws + ((size_t)14 << 20));       // [14, 30 MiB)
  size_t off = 33554432;
  float* xA   = (float*)(ws + off); off += 4194304;
  float* xB   = (float*)(ws + off); off += 4194304;
  float* zs   = (float*)(ws + off); off += 4194304;
  float* cvb  = (float*)(ws + off); off += 4194304;
  int*   idxb = (int*)  (ws + off); off += 655360;
  float* xxb  = (float*)(ws + off); off += 32768;
  float* fuse = (float*)(ws + off); off += 2097152;
  float* emb1 = (float*)(ws + off); off += 1048576;
  float* emb2 = (float*)(ws + off); off += 1048576;
  float* pool1= (float*)(ws + off); off += 4096;
  float* pool2= (float*)(ws + off); off += 4096;

  auto knn = [&](const float* xin, int C){
    k_gram<<<dim3(16,16,8), 256, 0, stream>>>(xin, xxb, nd, C);
    k_topk<<<BD*ND/4, 256, 0, stream>>>(nd, idxb);
  };
  auto phA = [&](const float* xin, int C, int O, const float* W, const float* bb,
                 const float* gg, const float* be){
    if (O == 64)       k_phaseA<64> <<<BD*ND/32, 256, 0, stream>>>(xin, W, bb, gg, be, zs, cvb, C);
    else if (O == 128) k_phaseA<128><<<BD*ND/32, 256, 0, stream>>>(xin, W, bb, gg, be, zs, cvb, C);
    else               k_phaseA<32> <<<BD*ND/32, 256, 0, stream>>>(xin, W, bb, gg, be, zs, cvb, C);
  };

  for (int br = 0; br < 2; ++br){
    const float* feat = feats[br];
    float* emb    = br ? emb2  : emb1;
    float* sout   = out + 8 + br*(BD*ND);
    float* pooled = br ? pool2 : pool1;
    for (int part = 0; part < 2; ++part){
      int c0 = part ? 3 : 0;
      int C0 = part ? 12 : 3;
      const float* const* Wl = part ? sw : cw;
      const float* const* bl = part ? sb : cb;
      const float* const* gl = part ? sg : cg;
      const float* const* Bl = part ? sB : cB;
      // layer 0: C0 -> 64
      { int elems = BD*ND*C0;
        k_transpose_in<<<(elems+255)/256, 256, 0, stream>>>(feat, xA, c0, C0); }
      k_xx<<<BD*ND/256, 256, 0, stream>>>(xA, xxb, C0);
      knn(xA, C0);
      phA(xA, C0, 64, Wl[0], bl[0], gl[0], Bl[0]);
      k_phaseB<true><<<BD*ND/4, 256, 0, stream>>>(zs, cvb, idxb, xB, xxb, 64, 64, 0);
      // layer 1: 64 -> 128 (xx already produced by phaseB)
      knn(xB, 64);
      phA(xB, 64, 128, Wl[1], bl[1], gl[1], Bl[1]);
      k_phaseB<true><<<BD*ND/4, 256, 0, stream>>>(zs, cvb, idxb, xA, xxb, 128, 128, 0);
      // layer 2: 128 -> 32, written into fuse at column offset
      knn(xA, 128);
      phA(xA, 128, 32, Wl[2], bl[2], gl[2], Bl[2]);
      k_phaseB<false><<<BD*ND/4, 256, 0, stream>>>(zs, cvb, idxb, fuse, nullptr, 32, 64, part*32);
    }
    // MHA (flash-decode)
    k_lin<<<(BD*ND*192)/256, 256, 0, stream>>>(fuse, mha_wi, mha_bi, qkv);
    k_attn_part<<<BD*8*KSL, 256, 0, stream>>>(qkv, pmb, plb, paccb);
    k_attn_comb<<<(BD*8*ND)/256, 256, 0, stream>>>(pmb, plb, paccb, attno);
    k_projmean<<<(BD*ND*32)/256, 256, 0, stream>>>(attno, mha_wo, mha_bo, emb);
    // fused attention pool
    k_poolfuse<<<BD, 256, 0, stream>>>(emb, att_w, sout, pooled);
  }
  k_head<<<1, 256, 0, stream>>>(pool1, pool2, ntn_w, ntn_v, ntn_b,
                                fc1_w, fc1_b, sc_w, sc_b, out);
}